// Round 1
// baseline (59.745 us; speedup 1.0000x reference)
//
#include <hip/hip_runtime.h>

// out[b] = cos(x[b,0])*cos(x[b,1])*cos(x[b,3]) * cos(w0)*cos(w1)*cos(w3)
// Derivation: product state through 1q gates; <Z_q> = cos(x_q)cos(w_q);
// CNOT ring is GF(2)-linear, ZZZI sign parity pulls back to bits {0,1,3};
// qubit-2 factor sums to 1.
__global__ __launch_bounds__(256) void qlayer_kernel(
    const float* __restrict__ x,
    const float* __restrict__ w,
    float* __restrict__ out,
    int B) {
    int i = blockIdx.x * blockDim.x + threadIdx.x;
    // uniform scalar: weight product (s_load + 3 cos, negligible)
    float cw = cosf(w[0]) * cosf(w[1]) * cosf(w[3]);
    if (i < B) {
        float4 xv = reinterpret_cast<const float4*>(x)[i];
        out[i] = cosf(xv.x) * cosf(xv.y) * cosf(xv.w) * cw;
    }
}

extern "C" void kernel_launch(void* const* d_in, const int* in_sizes, int n_in,
                              void* d_out, int out_size, void* d_ws, size_t ws_size,
                              hipStream_t stream) {
    const float* x = (const float*)d_in[0];
    const float* w = (const float*)d_in[1];
    float* out = (float*)d_out;
    int B = in_sizes[0] / 4;
    int block = 256;
    int grid = (B + block - 1) / block;
    qlayer_kernel<<<grid, block, 0, stream>>>(x, w, out, B);
}